// Round 1
// baseline (444.586 us; speedup 1.0000x reference)
//
#include <hip/hip_runtime.h>
#include <hip/hip_bf16.h>
#include <math.h>

#define NTOT 16384
#define HDIM 256
#define BBATCH 4
#define NSEQ 4096
#define FDIM 256
#define NE 262144
#define NEE (NE + NTOT)
#define NLAYER 3
#define LN_EPS 1e-5f
#define SLOPE 0.2f

// ---- workspace layout (bytes) ----
#define OFF_HA   0u            // float[NTOT*HDIM]  16777216
#define OFF_HW   16777216u     // float[NTOT*HDIM]  16777216
#define OFF_S    33554432u     // float[NTOT]       65536
#define OFF_D    33619968u     // float[NTOT]       65536
#define OFF_CNT  33685504u     // int[NTOT]         65536
#define OFF_OFF  33751040u     // int[NTOT+1]       65540 (pad 65792)
#define OFF_CUR  33816832u     // int[NTOT]         65536
#define OFF_CSR  33882368u     // int[NEE]          1114112
#define OFF_WT   34996480u     // float[3*FDIM*HDIM] 786432
// total ~35.8 MB

// transpose conv weight w[c][f][k] -> wT[k][f][c] so conv reads are coalesced in c
__global__ __launch_bounds__(256) void k_transpose_w(const float* __restrict__ w, float* __restrict__ wT) {
    int c = threadIdx.x;
    int fk = blockIdx.x;          // 0..767 = f*3+k
    int f = fk / 3, k = fk - 3 * f;
    wT[(k * FDIM + f) * HDIM + c] = w[c * 768 + fk];
}

// temporal conv (k=3, pad 1) + bias + residual + relu -> h0[NTOT][HDIM]
__global__ __launch_bounds__(256) void k_conv(const float* __restrict__ x, const float* __restrict__ wT,
                                              const float* __restrict__ tcb, float* __restrict__ h0) {
    __shared__ float xs[FDIM * 24];   // xs[f*24 + j], j=0..17 -> n = n0 + j - 1
    int blk = blockIdx.x;
    int b = blk >> 8;                 // 256 blocks per batch (N/16)
    int n0 = (blk & 255) * 16;
    int tid = threadIdx.x;
    const float* xb = x + (size_t)b * NSEQ * FDIM;
    #pragma unroll
    for (int j = 0; j < 18; ++j) {
        int g = n0 + j - 1;
        float v = (g >= 0 && g < NSEQ) ? xb[(size_t)g * FDIM + tid] : 0.f;
        xs[tid * 24 + j] = v;
    }
    __syncthreads();
    int c = tid;
    float acc[16];
    #pragma unroll
    for (int t = 0; t < 16; ++t) acc[t] = 0.f;
    for (int f = 0; f < FDIM; ++f) {
        float X[18];
        const float* xr = &xs[f * 24];
        #pragma unroll
        for (int j = 0; j < 18; ++j) X[j] = xr[j];
        float w0 = wT[(0 * FDIM + f) * HDIM + c];
        float w1 = wT[(1 * FDIM + f) * HDIM + c];
        float w2 = wT[(2 * FDIM + f) * HDIM + c];
        #pragma unroll
        for (int t = 0; t < 16; ++t) {
            acc[t] = fmaf(w0, X[t], acc[t]);
            acc[t] = fmaf(w1, X[t + 1], acc[t]);
            acc[t] = fmaf(w2, X[t + 2], acc[t]);
        }
    }
    float bc = tcb[c];
    #pragma unroll
    for (int t = 0; t < 16; ++t) {
        float v = acc[t] + bc + xs[c * 24 + t + 1];   // residual = x itself (F==H)
        v = v > 0.f ? v : 0.f;
        h0[((size_t)(b * NSEQ + n0 + t)) * HDIM + c] = v;
    }
}

// hw = h @ W   (16 rows per block; thread covers 4 rows x 4 cols)
__global__ __launch_bounds__(256) void k_gemm(const float* __restrict__ h, const float* __restrict__ W,
                                              float* __restrict__ out) {
    __shared__ float hs[16 * HDIM];
    int blk = blockIdx.x, tid = threadIdx.x;
    const float* hb = h + (size_t)blk * 16 * HDIM;
    #pragma unroll
    for (int i = 0; i < 16; ++i) hs[i * HDIM + tid] = hb[i * HDIM + tid];
    __syncthreads();
    int tc = tid & 63, tr = tid >> 6;
    float acc[4][4];
    #pragma unroll
    for (int r = 0; r < 4; ++r)
        #pragma unroll
        for (int q = 0; q < 4; ++q) acc[r][q] = 0.f;
    const float4* W4 = (const float4*)W;
    for (int f = 0; f < HDIM; ++f) {
        float4 wv = W4[f * 64 + tc];
        #pragma unroll
        for (int r = 0; r < 4; ++r) {
            float hv = hs[(tr * 4 + r) * HDIM + f];
            acc[r][0] = fmaf(hv, wv.x, acc[r][0]);
            acc[r][1] = fmaf(hv, wv.y, acc[r][1]);
            acc[r][2] = fmaf(hv, wv.z, acc[r][2]);
            acc[r][3] = fmaf(hv, wv.w, acc[r][3]);
        }
    }
    float4* o4 = (float4*)out;
    #pragma unroll
    for (int r = 0; r < 4; ++r)
        o4[((size_t)(blk * 16 + tr * 4 + r)) * 64 + tc] =
            make_float4(acc[r][0], acc[r][1], acc[r][2], acc[r][3]);
}

// per-node attention scalars s=hw.a_s, d=hw.a_d  (one wave per row)
__global__ __launch_bounds__(256) void k_sd(const float* __restrict__ hw, const float* __restrict__ as,
                                            const float* __restrict__ ad, float* __restrict__ s,
                                            float* __restrict__ d) {
    int tid = threadIdx.x;
    int wave = tid >> 6, lane = tid & 63;
    int row = blockIdx.x * 4 + wave;
    const float4* hv = (const float4*)(hw + (size_t)row * HDIM);
    const float4* as4 = (const float4*)as;
    const float4* ad4 = (const float4*)ad;
    float4 v = hv[lane], a = as4[lane], b = ad4[lane];
    float ss = v.x * a.x + v.y * a.y + v.z * a.z + v.w * a.w;
    float dd = v.x * b.x + v.y * b.y + v.z * b.z + v.w * b.w;
    #pragma unroll
    for (int o = 1; o < 64; o <<= 1) { ss += __shfl_xor(ss, o); dd += __shfl_xor(dd, o); }
    if (lane == 0) { s[row] = ss; d[row] = dd; }
}

__global__ __launch_bounds__(256) void k_count(const int* __restrict__ ei, int* __restrict__ cnt) {
    int e = blockIdx.x * 256 + threadIdx.x;
    int dst = (e < NE) ? ei[NE + e] : (e - NE);
    atomicAdd(&cnt[dst], 1);
}

__global__ __launch_bounds__(1024) void k_scan(const int* __restrict__ cnt, int* __restrict__ off,
                                               int* __restrict__ cur) {
    __shared__ int sums[1024];
    int t = threadIdx.x;
    int base = t * 16;
    int c[16]; int s = 0;
    #pragma unroll
    for (int j = 0; j < 16; ++j) { c[j] = cnt[base + j]; s += c[j]; }
    sums[t] = s;
    __syncthreads();
    for (int dstep = 1; dstep < 1024; dstep <<= 1) {
        int v = (t >= dstep) ? sums[t - dstep] : 0;
        __syncthreads();
        sums[t] += v;
        __syncthreads();
    }
    int pre = (t == 0) ? 0 : sums[t - 1];
    #pragma unroll
    for (int j = 0; j < 16; ++j) { off[base + j] = pre; cur[base + j] = pre; pre += c[j]; }
    if (t == 1023) off[NTOT] = pre;
}

__global__ __launch_bounds__(256) void k_scatter(const int* __restrict__ ei, int* __restrict__ cur,
                                                 int* __restrict__ csr) {
    int e = blockIdx.x * 256 + threadIdx.x;
    int src, dst;
    if (e < NE) { src = ei[e]; dst = ei[NE + e]; } else { src = dst = e - NE; }
    int pos = atomicAdd(&cur[dst], 1);
    csr[pos] = src;
}

// edge softmax + weighted aggregate; one wave per dst node
__global__ __launch_bounds__(256) void k_agg(const float* __restrict__ hw, const float* __restrict__ s,
                                             const float* __restrict__ d, const int* __restrict__ off,
                                             const int* __restrict__ csr, const float* __restrict__ bias,
                                             float* __restrict__ hout) {
    int tid = threadIdx.x;
    int wave = tid >> 6, lane = tid & 63;
    int node = blockIdx.x * 4 + wave;
    int beg = off[node], end = off[node + 1];
    float di = d[node];
    float m = -INFINITY;
    for (int j = beg; j < end; ++j) {
        int sj = csr[j];
        float e = s[sj] + di;
        e = e > 0.f ? e : SLOPE * e;
        m = fmaxf(m, e);
    }
    const float4* hv = (const float4*)hw;
    float4 acc = make_float4(0.f, 0.f, 0.f, 0.f);
    float denom = 0.f;
    for (int j = beg; j < end; ++j) {
        int sj = csr[j];
        float e = s[sj] + di;
        e = e > 0.f ? e : SLOPE * e;
        float wgt = expf(e - m);
        denom += wgt;
        float4 v = hv[(size_t)sj * 64 + lane];
        acc.x = fmaf(wgt, v.x, acc.x);
        acc.y = fmaf(wgt, v.y, acc.y);
        acc.z = fmaf(wgt, v.z, acc.z);
        acc.w = fmaf(wgt, v.w, acc.w);
    }
    float inv = 1.f / denom;
    const float4* b4 = (const float4*)bias;
    float4 bb = b4[lane];
    float4 o;
    o.x = acc.x * inv + bb.x; o.x = o.x > 0.f ? o.x : 0.f;
    o.y = acc.y * inv + bb.y; o.y = o.y > 0.f ? o.y : 0.f;
    o.z = acc.z * inv + bb.z; o.z = o.z > 0.f ? o.z : 0.f;
    o.w = acc.w * inv + bb.w; o.w = o.w > 0.f ? o.w : 0.f;
    ((float4*)hout)[(size_t)node * 64 + lane] = o;
}

// final conv at n==0 only (taps k=1,2 hit nodes n=0,1) + LayerNorm + relu
__global__ __launch_bounds__(256) void k_final(const float* __restrict__ h, const float* __restrict__ wT,
                                               const float* __restrict__ tcb, const float* __restrict__ g,
                                               const float* __restrict__ bln, float* __restrict__ out) {
    __shared__ float r0[HDIM], r1[HDIM];
    __shared__ float red[16];
    int b = blockIdx.x, c = threadIdx.x;
    r0[c] = h[(size_t)(b * NSEQ + 0) * HDIM + c];
    r1[c] = h[(size_t)(b * NSEQ + 1) * HDIM + c];
    __syncthreads();
    float a = tcb[c];
    for (int f = 0; f < FDIM; ++f) {
        a = fmaf(wT[(1 * FDIM + f) * HDIM + c], r0[f], a);
        a = fmaf(wT[(2 * FDIM + f) * HDIM + c], r1[f], a);
    }
    float ss = a, sq = a * a;
    #pragma unroll
    for (int o = 1; o < 64; o <<= 1) { ss += __shfl_xor(ss, o); sq += __shfl_xor(sq, o); }
    int wave = c >> 6, lane = c & 63;
    if (lane == 0) { red[wave] = ss; red[8 + wave] = sq; }
    __syncthreads();
    float tot = 0.f, totq = 0.f;
    #pragma unroll
    for (int w = 0; w < 4; ++w) { tot += red[w]; totq += red[8 + w]; }
    float mu = tot * (1.f / HDIM);
    float var = totq * (1.f / HDIM) - mu * mu;
    float v = (a - mu) * rsqrtf(var + LN_EPS) * g[c] + bln[c];
    out[b * HDIM + c] = v > 0.f ? v : 0.f;
}

extern "C" void kernel_launch(void* const* d_in, const int* in_sizes, int n_in,
                              void* d_out, int out_size, void* d_ws, size_t ws_size,
                              hipStream_t stream) {
    const float* x     = (const float*)d_in[0];
    const int*   ei    = (const int*)d_in[1];
    const float* tcw   = (const float*)d_in[2];
    const float* tcb   = (const float*)d_in[3];
    const float* gatW  = (const float*)d_in[4];
    const float* gatas = (const float*)d_in[5];
    const float* gatad = (const float*)d_in[6];
    const float* gatb  = (const float*)d_in[7];
    const float* lng   = (const float*)d_in[8];
    const float* lnb   = (const float*)d_in[9];
    float* out = (float*)d_out;

    char* ws = (char*)d_ws;
    float* hA   = (float*)(ws + OFF_HA);
    float* hw   = (float*)(ws + OFF_HW);
    float* sArr = (float*)(ws + OFF_S);
    float* dArr = (float*)(ws + OFF_D);
    int*   cnt  = (int*)(ws + OFF_CNT);
    int*   offA = (int*)(ws + OFF_OFF);
    int*   cur  = (int*)(ws + OFF_CUR);
    int*   csr  = (int*)(ws + OFF_CSR);
    float* wT   = (float*)(ws + OFF_WT);

    hipMemsetAsync(cnt, 0, NTOT * sizeof(int), stream);

    k_transpose_w<<<768, 256, 0, stream>>>(tcw, wT);
    k_conv<<<(BBATCH * NSEQ) / 16, 256, 0, stream>>>(x, wT, tcb, hA);

    // CSR build (dst-major)
    k_count<<<NEE / 256, 256, 0, stream>>>(ei, cnt);
    k_scan<<<1, 1024, 0, stream>>>(cnt, offA, cur);
    k_scatter<<<NEE / 256, 256, 0, stream>>>(ei, cur, csr);

    for (int l = 0; l < NLAYER; ++l) {
        k_gemm<<<NTOT / 16, 256, 0, stream>>>(hA, gatW + (size_t)l * HDIM * HDIM, hw);
        k_sd<<<NTOT / 4, 256, 0, stream>>>(hw, gatas + l * HDIM, gatad + l * HDIM, sArr, dArr);
        k_agg<<<NTOT / 4, 256, 0, stream>>>(hw, sArr, dArr, offA, csr, gatb + l * HDIM, hA);
    }

    k_final<<<BBATCH, 256, 0, stream>>>(hA, wT, tcb, lng, lnb, out);
}

// Round 2
// 292.784 us; speedup vs baseline: 1.5185x; 1.5185x over previous
//
#include <hip/hip_runtime.h>
#include <hip/hip_bf16.h>
#include <math.h>

#define NTOT 16384
#define HDIM 256
#define BBATCH 4
#define NSEQ 4096
#define FDIM 256
#define NE 262144
#define NEE (NE + NTOT)
#define NLAYER 3
#define LN_EPS 1e-5f
#define SLOPE 0.2f

typedef __attribute__((ext_vector_type(8))) short bf16x8;
typedef __attribute__((ext_vector_type(4))) float f32x4;

#define LDW 80   // LDS row stride in bytes (64B payload + 16B pad -> 2-way bank alias, free)

// ---- workspace layout (bytes) ----
#define OFF_HA   0u          // ushort[NTOT*256]  8388608   node features (bf16)
#define OFF_HW   8388608u    // ushort[NTOT*256]  8388608   hw = h@W (bf16)
#define OFF_XB   16777216u   // ushort[NTOT*256]  8388608   x in bf16
#define OFF_WC   25165824u   // ushort[256*768]   393216    conv weight^T bf16, k = tap*256+f
#define OFF_WL   25559040u   // ushort[3*256*256] 393216    layer W^T bf16
#define OFF_S    25952256u   // float[NTOT]
#define OFF_D    26017792u   // float[NTOT]
#define OFF_CNT  26083328u   // int[NTOT]
#define OFF_OFF  26148864u   // int[NTOT+1] (pad)
#define OFF_CUR  26214656u   // int[NTOT]
#define OFF_CSR  26280192u   // int[NEE] 1114112
#define OFF_WT   27394304u   // float[3*256*256] 786432  (fp32 conv weight^T for k_final)
// total 28180736

static __device__ __forceinline__ unsigned short f2b(float f) {
    __hip_bfloat16 h = __float2bfloat16(f);
    return __builtin_bit_cast(unsigned short, h);
}
static __device__ __forceinline__ float b2f(unsigned short u) {
    __hip_bfloat16 h = __builtin_bit_cast(__hip_bfloat16, u);
    return __bfloat162float(h);
}

// x fp32 -> bf16
__global__ __launch_bounds__(256) void k_xbf(const float* __restrict__ x, unsigned short* __restrict__ xb) {
    int i = (blockIdx.x * 256 + threadIdx.x) * 4;
    float4 v = *(const float4*)(x + i);
    ushort4 o;
    o.x = f2b(v.x); o.y = f2b(v.y); o.z = f2b(v.z); o.w = f2b(v.w);
    *(ushort4*)(xb + i) = o;
}

// conv weight tcw[c][f][tap] -> wcB[c][tap*256+f] (bf16)
__global__ __launch_bounds__(256) void k_prep_convw(const float* __restrict__ tcw, unsigned short* __restrict__ wcB) {
    int c = blockIdx.x, f = threadIdx.x;
    const float* s = tcw + c * 768 + f * 3;
    wcB[c * 768 + 0 * 256 + f] = f2b(s[0]);
    wcB[c * 768 + 1 * 256 + f] = f2b(s[1]);
    wcB[c * 768 + 2 * 256 + f] = f2b(s[2]);
}

// layer weight W[l][k][n] -> WT[l][n*256+k] (bf16)
__global__ __launch_bounds__(256) void k_prep_W(const float* __restrict__ W, unsigned short* __restrict__ WT) {
    int ln = blockIdx.x; int n = ln & 255; int l = ln >> 8; int k = threadIdx.x;
    WT[(size_t)l * 65536 + n * 256 + k] = f2b(W[(size_t)l * 65536 + k * 256 + n]);
}

// fp32 conv weight transpose for k_final: w[c][f][k] -> wT[k][f][c]
__global__ __launch_bounds__(256) void k_transpose_w(const float* __restrict__ w, float* __restrict__ wT) {
    int c = threadIdx.x;
    int fk = blockIdx.x;
    int f = fk / 3, k = fk - 3 * f;
    wT[(k * FDIM + f) * HDIM + c] = w[c * 768 + fk];
}

// ---------------- MFMA GEMM: hw = h @ W  (M=16384, N=256, K=256) ----------------
// BM=128, BN=64, BK=32; 4 waves in 2x2; wave tile 64x32 (4x2 16x16 frags)
__global__ __launch_bounds__(256) void k_gemm_layer(const unsigned short* __restrict__ hAb,
                                                    const unsigned short* __restrict__ WT,
                                                    unsigned short* __restrict__ hwB) {
    __shared__ char lds[128 * LDW + 64 * LDW];
    char* As = lds;
    char* Bs = lds + 128 * LDW;
    int t = threadIdx.x;
    int m0 = blockIdx.x * 128, n0 = blockIdx.y * 64;
    int w = t >> 6, lane = t & 63;
    int wr = w >> 1, wc = w & 1;
    int row16 = lane & 15, kg = lane >> 4;
    int rA = t >> 1, hh = t & 1;
    f32x4 acc[4][2];
    #pragma unroll
    for (int mi = 0; mi < 4; ++mi)
        #pragma unroll
        for (int ni = 0; ni < 2; ++ni) acc[mi][ni] = (f32x4)(0.f);

    for (int kb = 0; kb < 256; kb += 32) {
        {   // A: 128 rows x 64B
            const uint4* src = (const uint4*)(hAb + (size_t)(m0 + rA) * 256 + kb + hh * 16);
            uint4 v0 = src[0], v1 = src[1];
            *(uint4*)&As[rA * LDW + hh * 32] = v0;
            *(uint4*)&As[rA * LDW + hh * 32 + 16] = v1;
        }
        if (t < 128) {  // B: 64 rows x 64B
            int rB = t >> 1;
            const uint4* src = (const uint4*)(WT + (size_t)(n0 + rB) * 256 + kb + hh * 16);
            uint4 v0 = src[0], v1 = src[1];
            *(uint4*)&Bs[rB * LDW + hh * 32] = v0;
            *(uint4*)&Bs[rB * LDW + hh * 32 + 16] = v1;
        }
        __syncthreads();
        bf16x8 bfr[2];
        #pragma unroll
        for (int ni = 0; ni < 2; ++ni)
            bfr[ni] = *(bf16x8*)&Bs[(wc * 32 + ni * 16 + row16) * LDW + kg * 16];
        #pragma unroll
        for (int mi = 0; mi < 4; ++mi) {
            bf16x8 afr = *(bf16x8*)&As[(wr * 64 + mi * 16 + row16) * LDW + kg * 16];
            acc[mi][0] = __builtin_amdgcn_mfma_f32_16x16x32_bf16(afr, bfr[0], acc[mi][0], 0, 0, 0);
            acc[mi][1] = __builtin_amdgcn_mfma_f32_16x16x32_bf16(afr, bfr[1], acc[mi][1], 0, 0, 0);
        }
        __syncthreads();
    }
    #pragma unroll
    for (int mi = 0; mi < 4; ++mi)
        #pragma unroll
        for (int ni = 0; ni < 2; ++ni) {
            int rowl = wr * 64 + mi * 16 + kg * 4;
            int coll = wc * 32 + ni * 16 + row16;
            size_t base = (size_t)(m0 + rowl) * 256 + n0 + coll;
            #pragma unroll
            for (int q = 0; q < 4; ++q) hwB[base + (size_t)q * 256] = f2b(acc[mi][ni][q]);
        }
}

// ---------------- MFMA conv GEMM: M=16384, N=256, K=768 (k = tap*256+f) ----------------
// out = relu(conv + bias + x_fp32) -> hA (bf16)
__global__ __launch_bounds__(256) void k_conv_gemm(const unsigned short* __restrict__ xbf,
                                                   const float* __restrict__ x,
                                                   const unsigned short* __restrict__ wcB,
                                                   const float* __restrict__ tcb,
                                                   unsigned short* __restrict__ hAb) {
    __shared__ char lds[128 * LDW + 64 * LDW];
    char* As = lds;
    char* Bs = lds + 128 * LDW;
    int t = threadIdx.x;
    int m0 = blockIdx.x * 128, n0 = blockIdx.y * 64;
    int bb = m0 >> 12;          // batch
    int nloc0 = m0 & 4095;
    int w = t >> 6, lane = t & 63;
    int wr = w >> 1, wc = w & 1;
    int row16 = lane & 15, kg = lane >> 4;
    int rA = t >> 1, hh = t & 1;
    f32x4 acc[4][2];
    #pragma unroll
    for (int mi = 0; mi < 4; ++mi)
        #pragma unroll
        for (int ni = 0; ni < 2; ++ni) acc[mi][ni] = (f32x4)(0.f);

    for (int kb = 0; kb < 768; kb += 32) {
        int tap = kb >> 8;
        int fb = kb & 255;
        {   // A: rows are nodes shifted by tap-1, zero-padded at batch edges
            int nl = nloc0 + rA + tap - 1;
            uint4 v0 = make_uint4(0, 0, 0, 0), v1 = make_uint4(0, 0, 0, 0);
            if ((unsigned)nl < 4096u) {
                const uint4* src = (const uint4*)(xbf + ((size_t)(bb << 12) + nl) * 256 + fb + hh * 16);
                v0 = src[0]; v1 = src[1];
            }
            *(uint4*)&As[rA * LDW + hh * 32] = v0;
            *(uint4*)&As[rA * LDW + hh * 32 + 16] = v1;
        }
        if (t < 128) {  // B: wcB row stride 768
            int rB = t >> 1;
            const uint4* src = (const uint4*)(wcB + (size_t)(n0 + rB) * 768 + kb + hh * 16);
            uint4 v0 = src[0], v1 = src[1];
            *(uint4*)&Bs[rB * LDW + hh * 32] = v0;
            *(uint4*)&Bs[rB * LDW + hh * 32 + 16] = v1;
        }
        __syncthreads();
        bf16x8 bfr[2];
        #pragma unroll
        for (int ni = 0; ni < 2; ++ni)
            bfr[ni] = *(bf16x8*)&Bs[(wc * 32 + ni * 16 + row16) * LDW + kg * 16];
        #pragma unroll
        for (int mi = 0; mi < 4; ++mi) {
            bf16x8 afr = *(bf16x8*)&As[(wr * 64 + mi * 16 + row16) * LDW + kg * 16];
            acc[mi][0] = __builtin_amdgcn_mfma_f32_16x16x32_bf16(afr, bfr[0], acc[mi][0], 0, 0, 0);
            acc[mi][1] = __builtin_amdgcn_mfma_f32_16x16x32_bf16(afr, bfr[1], acc[mi][1], 0, 0, 0);
        }
        __syncthreads();
    }
    #pragma unroll
    for (int mi = 0; mi < 4; ++mi)
        #pragma unroll
        for (int ni = 0; ni < 2; ++ni) {
            int rowl = wr * 64 + mi * 16 + kg * 4;
            int coll = wc * 32 + ni * 16 + row16;
            int n = n0 + coll;
            float bc = tcb[n];
            #pragma unroll
            for (int q = 0; q < 4; ++q) {
                size_t node = (size_t)(m0 + rowl + q);
                float v = acc[mi][ni][q] + bc + x[node * 256 + n];  // exact fp32 residual
                v = v > 0.f ? v : 0.f;
                hAb[node * 256 + n] = f2b(v);
            }
        }
}

// per-node attention scalars from bf16 hw
__global__ __launch_bounds__(256) void k_sd(const unsigned short* __restrict__ hwB,
                                            const float* __restrict__ as, const float* __restrict__ ad,
                                            float* __restrict__ s, float* __restrict__ d) {
    int tid = threadIdx.x;
    int wave = tid >> 6, lane = tid & 63;
    int row = blockIdx.x * 4 + wave;
    ushort4 v = ((const ushort4*)(hwB + (size_t)row * 256))[lane];
    float4 a = ((const float4*)as)[lane];
    float4 b = ((const float4*)ad)[lane];
    float vx = b2f(v.x), vy = b2f(v.y), vz = b2f(v.z), vw = b2f(v.w);
    float ss = vx * a.x + vy * a.y + vz * a.z + vw * a.w;
    float dd = vx * b.x + vy * b.y + vz * b.z + vw * b.w;
    #pragma unroll
    for (int o = 1; o < 64; o <<= 1) { ss += __shfl_xor(ss, o); dd += __shfl_xor(dd, o); }
    if (lane == 0) { s[row] = ss; d[row] = dd; }
}

__global__ __launch_bounds__(256) void k_count(const int* __restrict__ ei, int* __restrict__ cnt) {
    int e = blockIdx.x * 256 + threadIdx.x;
    int dst = (e < NE) ? ei[NE + e] : (e - NE);
    atomicAdd(&cnt[dst], 1);
}

__global__ __launch_bounds__(1024) void k_scan(const int* __restrict__ cnt, int* __restrict__ off,
                                               int* __restrict__ cur) {
    __shared__ int sums[1024];
    int t = threadIdx.x;
    int base = t * 16;
    int c[16]; int s = 0;
    #pragma unroll
    for (int j = 0; j < 16; ++j) { c[j] = cnt[base + j]; s += c[j]; }
    sums[t] = s;
    __syncthreads();
    for (int dstep = 1; dstep < 1024; dstep <<= 1) {
        int v = (t >= dstep) ? sums[t - dstep] : 0;
        __syncthreads();
        sums[t] += v;
        __syncthreads();
    }
    int pre = (t == 0) ? 0 : sums[t - 1];
    #pragma unroll
    for (int j = 0; j < 16; ++j) { off[base + j] = pre; cur[base + j] = pre; pre += c[j]; }
    if (t == 1023) off[NTOT] = pre;
}

__global__ __launch_bounds__(256) void k_scatter(const int* __restrict__ ei, int* __restrict__ cur,
                                                 int* __restrict__ csr) {
    int e = blockIdx.x * 256 + threadIdx.x;
    int src, dst;
    if (e < NE) { src = ei[e]; dst = ei[NE + e]; } else { src = dst = e - NE; }
    int pos = atomicAdd(&cur[dst], 1);
    csr[pos] = src;
}

// edge softmax + weighted aggregate (bf16 gather); one wave per dst node
__global__ __launch_bounds__(256) void k_agg(const unsigned short* __restrict__ hwB,
                                             const float* __restrict__ s, const float* __restrict__ d,
                                             const int* __restrict__ off, const int* __restrict__ csr,
                                             const float* __restrict__ bias,
                                             unsigned short* __restrict__ hout) {
    int tid = threadIdx.x;
    int wave = tid >> 6, lane = tid & 63;
    int node = blockIdx.x * 4 + wave;
    int beg = off[node], end = off[node + 1];
    float di = d[node];
    float m = -INFINITY;
    for (int j = beg; j < end; ++j) {
        int sj = csr[j];
        float e = s[sj] + di;
        e = e > 0.f ? e : SLOPE * e;
        m = fmaxf(m, e);
    }
    float a0 = 0.f, a1 = 0.f, a2 = 0.f, a3 = 0.f;
    float denom = 0.f;
    for (int j = beg; j < end; ++j) {
        int sj = csr[j];
        float e = s[sj] + di;
        e = e > 0.f ? e : SLOPE * e;
        float wgt = __expf(e - m);
        denom += wgt;
        ushort4 v = ((const ushort4*)(hwB + (size_t)sj * 256))[lane];
        a0 = fmaf(wgt, b2f(v.x), a0);
        a1 = fmaf(wgt, b2f(v.y), a1);
        a2 = fmaf(wgt, b2f(v.z), a2);
        a3 = fmaf(wgt, b2f(v.w), a3);
    }
    float inv = 1.f / denom;
    float4 bb = ((const float4*)bias)[lane];
    ushort4 o;
    float o0 = a0 * inv + bb.x; o.x = f2b(o0 > 0.f ? o0 : 0.f);
    float o1 = a1 * inv + bb.y; o.y = f2b(o1 > 0.f ? o1 : 0.f);
    float o2 = a2 * inv + bb.z; o.z = f2b(o2 > 0.f ? o2 : 0.f);
    float o3 = a3 * inv + bb.w; o.w = f2b(o3 > 0.f ? o3 : 0.f);
    ((ushort4*)hout)[(size_t)node * 64 + lane] = o;
}

// final conv at n==0 (taps 1,2 on nodes 0,1) + LayerNorm + relu
__global__ __launch_bounds__(256) void k_final(const unsigned short* __restrict__ hAb,
                                               const float* __restrict__ wT,
                                               const float* __restrict__ tcb, const float* __restrict__ g,
                                               const float* __restrict__ bln, float* __restrict__ out) {
    __shared__ float r0[HDIM], r1[HDIM];
    __shared__ float red[16];
    int b = blockIdx.x, c = threadIdx.x;
    r0[c] = b2f(hAb[(size_t)(b * NSEQ + 0) * HDIM + c]);
    r1[c] = b2f(hAb[(size_t)(b * NSEQ + 1) * HDIM + c]);
    __syncthreads();
    float a = tcb[c];
    for (int f = 0; f < FDIM; ++f) {
        a = fmaf(wT[(1 * FDIM + f) * HDIM + c], r0[f], a);
        a = fmaf(wT[(2 * FDIM + f) * HDIM + c], r1[f], a);
    }
    float ss = a, sq = a * a;
    #pragma unroll
    for (int o = 1; o < 64; o <<= 1) { ss += __shfl_xor(ss, o); sq += __shfl_xor(sq, o); }
    int wave = c >> 6, lane = c & 63;
    if (lane == 0) { red[wave] = ss; red[8 + wave] = sq; }
    __syncthreads();
    float tot = 0.f, totq = 0.f;
    #pragma unroll
    for (int w = 0; w < 4; ++w) { tot += red[w]; totq += red[8 + w]; }
    float mu = tot * (1.f / HDIM);
    float var = totq * (1.f / HDIM) - mu * mu;
    float v = (a - mu) * rsqrtf(var + LN_EPS) * g[c] + bln[c];
    out[b * HDIM + c] = v > 0.f ? v : 0.f;
}

extern "C" void kernel_launch(void* const* d_in, const int* in_sizes, int n_in,
                              void* d_out, int out_size, void* d_ws, size_t ws_size,
                              hipStream_t stream) {
    const float* x     = (const float*)d_in[0];
    const int*   ei    = (const int*)d_in[1];
    const float* tcw   = (const float*)d_in[2];
    const float* tcb   = (const float*)d_in[3];
    const float* gatW  = (const float*)d_in[4];
    const float* gatas = (const float*)d_in[5];
    const float* gatad = (const float*)d_in[6];
    const float* gatb  = (const float*)d_in[7];
    const float* lng   = (const float*)d_in[8];
    const float* lnb   = (const float*)d_in[9];
    float* out = (float*)d_out;

    char* ws = (char*)d_ws;
    unsigned short* hAb = (unsigned short*)(ws + OFF_HA);
    unsigned short* hwB = (unsigned short*)(ws + OFF_HW);
    unsigned short* xbf = (unsigned short*)(ws + OFF_XB);
    unsigned short* wcB = (unsigned short*)(ws + OFF_WC);
    unsigned short* WTb = (unsigned short*)(ws + OFF_WL);
    float* sArr = (float*)(ws + OFF_S);
    float* dArr = (float*)(ws + OFF_D);
    int*   cnt  = (int*)(ws + OFF_CNT);
    int*   offA = (int*)(ws + OFF_OFF);
    int*   cur  = (int*)(ws + OFF_CUR);
    int*   csr  = (int*)(ws + OFF_CSR);
    float* wT   = (float*)(ws + OFF_WT);

    hipMemsetAsync(cnt, 0, NTOT * sizeof(int), stream);

    k_xbf<<<NTOT * HDIM / 1024, 256, 0, stream>>>(x, xbf);
    k_prep_convw<<<256, 256, 0, stream>>>(tcw, wcB);
    k_prep_W<<<768, 256, 0, stream>>>(gatW, WTb);
    k_transpose_w<<<768, 256, 0, stream>>>(tcw, wT);

    // CSR build (dst-major)
    k_count<<<NEE / 256, 256, 0, stream>>>(ei, cnt);
    k_scan<<<1, 1024, 0, stream>>>(cnt, offA, cur);
    k_scatter<<<NEE / 256, 256, 0, stream>>>(ei, cur, csr);

    k_conv_gemm<<<dim3(NTOT / 128, 4), 256, 0, stream>>>(xbf, x, wcB, tcb, hAb);

    for (int l = 0; l < NLAYER; ++l) {
        k_gemm_layer<<<dim3(NTOT / 128, 4), 256, 0, stream>>>(hAb, WTb + (size_t)l * 65536, hwB);
        k_sd<<<NTOT / 4, 256, 0, stream>>>(hwB, gatas + l * HDIM, gatad + l * HDIM, sArr, dArr);
        k_agg<<<NTOT / 4, 256, 0, stream>>>(hwB, sArr, dArr, offA, csr, gatb + l * HDIM, hAb);
    }

    k_final<<<BBATCH, 256, 0, stream>>>(hAb, wT, tcb, lng, lnb, out);
}

// Round 3
// 200.176 us; speedup vs baseline: 2.2210x; 1.4626x over previous
//
#include <hip/hip_runtime.h>
#include <hip/hip_bf16.h>
#include <math.h>

#define NTOT 16384
#define HDIM 256
#define BBATCH 4
#define NSEQ 4096
#define FDIM 256
#define NE 262144
#define NEE (NE + NTOT)
#define NLAYER 3
#define LN_EPS 1e-5f
#define SLOPE 0.2f

typedef __attribute__((ext_vector_type(8))) short bf16x8;
typedef __attribute__((ext_vector_type(4))) float f32x4;

#define LDW 80   // LDS row stride in bytes (64B payload + 16B pad -> 2-way bank alias, free)

// ---- workspace layout (bytes) ----
#define OFF_HA   0u          // ushort[NTOT*256]  8388608   node features (bf16)
#define OFF_HW   8388608u    // ushort[NTOT*256]  8388608   hw = h@W (bf16)
#define OFF_XB   16777216u   // ushort[NTOT*256]  8388608   x in bf16
#define OFF_WC   25165824u   // ushort[256*768]   393216    conv weight^T bf16, k = tap*256+f
#define OFF_WL   25559040u   // ushort[3*256*256] 393216    layer W^T bf16
#define OFF_SP   25952256u   // float[4*NTOT]     262144    s partials (per col-block)
#define OFF_DP   26214400u   // float[4*NTOT]     262144    d partials
#define OFF_CNT  26476544u   // int[NTOT]
#define OFF_OFF  26542080u   // int[NTOT+1] (pad 65792)
#define OFF_CUR  26607872u   // int[NTOT]
#define OFF_CSR  26673408u   // int[NEE] 1114112
#define OFF_WT   27787520u   // float[3*256*256] 786432 (fp32 conv weight^T for k_final)
// total 28573952

static __device__ __forceinline__ unsigned short f2b(float f) {
    __hip_bfloat16 h = __float2bfloat16(f);
    return __builtin_bit_cast(unsigned short, h);
}
static __device__ __forceinline__ float b2f(unsigned short u) {
    __hip_bfloat16 h = __builtin_bit_cast(__hip_bfloat16, u);
    return __bfloat162float(h);
}
static __device__ __forceinline__ float rlanef(float v, int l) {
    return __builtin_bit_cast(float, __builtin_amdgcn_readlane(__builtin_bit_cast(int, v), l));
}

// x fp32 -> bf16
__global__ __launch_bounds__(256) void k_xbf(const float* __restrict__ x, unsigned short* __restrict__ xb) {
    int i = (blockIdx.x * 256 + threadIdx.x) * 4;
    float4 v = *(const float4*)(x + i);
    ushort4 o;
    o.x = f2b(v.x); o.y = f2b(v.y); o.z = f2b(v.z); o.w = f2b(v.w);
    *(ushort4*)(xb + i) = o;
}

// merged weight prep: conv w -> bf16 [c][tap*256+f]; gat W -> bf16 W^T; conv w -> fp32 wT[k][f][c]
__global__ __launch_bounds__(256) void k_prep(const float* __restrict__ tcw, const float* __restrict__ gatW,
                                              unsigned short* __restrict__ wcB, unsigned short* __restrict__ WTb,
                                              float* __restrict__ wT) {
    int b = blockIdx.x, t = threadIdx.x;
    if (b < 256) {
        const float* s = tcw + b * 768 + t * 3;
        wcB[b * 768 + 0 + t]   = f2b(s[0]);
        wcB[b * 768 + 256 + t] = f2b(s[1]);
        wcB[b * 768 + 512 + t] = f2b(s[2]);
    } else if (b < 1024) {
        int ln = b - 256; int n = ln & 255; int l = ln >> 8;
        WTb[(size_t)l * 65536 + n * 256 + t] = f2b(gatW[(size_t)l * 65536 + t * 256 + n]);
    } else {
        int fk = b - 1024; int f = fk / 3, k = fk - 3 * f;
        wT[(k * FDIM + f) * HDIM + t] = tcw[t * 768 + fk];
    }
}

// ---------------- MFMA GEMM: hw = h @ W (M=16384,N=256,K=256) + fused s/d partials ----------------
__global__ __launch_bounds__(256) void k_gemm_layer(const unsigned short* __restrict__ hAb,
                                                    const unsigned short* __restrict__ WT,
                                                    const float* __restrict__ as, const float* __restrict__ ad,
                                                    unsigned short* __restrict__ hwB,
                                                    float* __restrict__ sPart, float* __restrict__ dPart) {
    __shared__ char lds[128 * LDW + 64 * LDW];
    __shared__ float sRed[256], dRed[256];
    char* As = lds;
    char* Bs = lds + 128 * LDW;
    int t = threadIdx.x;
    int m0 = blockIdx.x * 128, n0 = blockIdx.y * 64;
    int w = t >> 6, lane = t & 63;
    int wr = w >> 1, wc = w & 1;
    int row16 = lane & 15, kg = lane >> 4;
    int rA = t >> 1, hh = t & 1;
    f32x4 acc[4][2];
    #pragma unroll
    for (int mi = 0; mi < 4; ++mi)
        #pragma unroll
        for (int ni = 0; ni < 2; ++ni) acc[mi][ni] = (f32x4)(0.f);

    for (int kb = 0; kb < 256; kb += 32) {
        {
            const uint4* src = (const uint4*)(hAb + (size_t)(m0 + rA) * 256 + kb + hh * 16);
            uint4 v0 = src[0], v1 = src[1];
            *(uint4*)&As[rA * LDW + hh * 32] = v0;
            *(uint4*)&As[rA * LDW + hh * 32 + 16] = v1;
        }
        if (t < 128) {
            int rB = t >> 1;
            const uint4* src = (const uint4*)(WT + (size_t)(n0 + rB) * 256 + kb + hh * 16);
            uint4 v0 = src[0], v1 = src[1];
            *(uint4*)&Bs[rB * LDW + hh * 32] = v0;
            *(uint4*)&Bs[rB * LDW + hh * 32 + 16] = v1;
        }
        __syncthreads();
        bf16x8 bfr[2];
        #pragma unroll
        for (int ni = 0; ni < 2; ++ni)
            bfr[ni] = *(bf16x8*)&Bs[(wc * 32 + ni * 16 + row16) * LDW + kg * 16];
        #pragma unroll
        for (int mi = 0; mi < 4; ++mi) {
            bf16x8 afr = *(bf16x8*)&As[(wr * 64 + mi * 16 + row16) * LDW + kg * 16];
            acc[mi][0] = __builtin_amdgcn_mfma_f32_16x16x32_bf16(afr, bfr[0], acc[mi][0], 0, 0, 0);
            acc[mi][1] = __builtin_amdgcn_mfma_f32_16x16x32_bf16(afr, bfr[1], acc[mi][1], 0, 0, 0);
        }
        __syncthreads();
    }
    // hw store
    #pragma unroll
    for (int mi = 0; mi < 4; ++mi)
        #pragma unroll
        for (int ni = 0; ni < 2; ++ni) {
            int rowl = wr * 64 + mi * 16 + kg * 4;
            int coll = wc * 32 + ni * 16 + row16;
            size_t base = (size_t)(m0 + rowl) * 256 + n0 + coll;
            #pragma unroll
            for (int q = 0; q < 4; ++q) hwB[base + (size_t)q * 256] = f2b(acc[mi][ni][q]);
        }
    // fused s/d partials over this block's 64 cols
    float asv0 = as[n0 + wc * 32 + row16];
    float asv1 = as[n0 + wc * 32 + 16 + row16];
    float adv0 = ad[n0 + wc * 32 + row16];
    float adv1 = ad[n0 + wc * 32 + 16 + row16];
    #pragma unroll
    for (int mi = 0; mi < 4; ++mi)
        #pragma unroll
        for (int q = 0; q < 4; ++q) {
            float ps = acc[mi][0][q] * asv0 + acc[mi][1][q] * asv1;
            float pd = acc[mi][0][q] * adv0 + acc[mi][1][q] * adv1;
            #pragma unroll
            for (int o = 1; o < 16; o <<= 1) { ps += __shfl_xor(ps, o); pd += __shfl_xor(pd, o); }
            if (row16 == 0) {
                int rowl = wr * 64 + mi * 16 + kg * 4 + q;
                sRed[rowl * 2 + wc] = ps;
                dRed[rowl * 2 + wc] = pd;
            }
        }
    __syncthreads();
    if (t < 128) {
        sPart[(size_t)blockIdx.y * NTOT + m0 + t] = sRed[t * 2] + sRed[t * 2 + 1];
        dPart[(size_t)blockIdx.y * NTOT + m0 + t] = dRed[t * 2] + dRed[t * 2 + 1];
    }
}

// ---------------- MFMA conv GEMM: M=16384, N=256, K=768 (k = tap*256+f) ----------------
__global__ __launch_bounds__(256) void k_conv_gemm(const unsigned short* __restrict__ xbf,
                                                   const float* __restrict__ x,
                                                   const unsigned short* __restrict__ wcB,
                                                   const float* __restrict__ tcb,
                                                   unsigned short* __restrict__ hAb) {
    __shared__ char lds[128 * LDW + 64 * LDW];
    char* As = lds;
    char* Bs = lds + 128 * LDW;
    int t = threadIdx.x;
    int m0 = blockIdx.x * 128, n0 = blockIdx.y * 64;
    int bb = m0 >> 12;
    int nloc0 = m0 & 4095;
    int w = t >> 6, lane = t & 63;
    int wr = w >> 1, wc = w & 1;
    int row16 = lane & 15, kg = lane >> 4;
    int rA = t >> 1, hh = t & 1;
    f32x4 acc[4][2];
    #pragma unroll
    for (int mi = 0; mi < 4; ++mi)
        #pragma unroll
        for (int ni = 0; ni < 2; ++ni) acc[mi][ni] = (f32x4)(0.f);

    for (int kb = 0; kb < 768; kb += 32) {
        int tap = kb >> 8;
        int fb = kb & 255;
        {
            int nl = nloc0 + rA + tap - 1;
            uint4 v0 = make_uint4(0, 0, 0, 0), v1 = make_uint4(0, 0, 0, 0);
            if ((unsigned)nl < 4096u) {
                const uint4* src = (const uint4*)(xbf + ((size_t)(bb << 12) + nl) * 256 + fb + hh * 16);
                v0 = src[0]; v1 = src[1];
            }
            *(uint4*)&As[rA * LDW + hh * 32] = v0;
            *(uint4*)&As[rA * LDW + hh * 32 + 16] = v1;
        }
        if (t < 128) {
            int rB = t >> 1;
            const uint4* src = (const uint4*)(wcB + (size_t)(n0 + rB) * 768 + kb + hh * 16);
            uint4 v0 = src[0], v1 = src[1];
            *(uint4*)&Bs[rB * LDW + hh * 32] = v0;
            *(uint4*)&Bs[rB * LDW + hh * 32 + 16] = v1;
        }
        __syncthreads();
        bf16x8 bfr[2];
        #pragma unroll
        for (int ni = 0; ni < 2; ++ni)
            bfr[ni] = *(bf16x8*)&Bs[(wc * 32 + ni * 16 + row16) * LDW + kg * 16];
        #pragma unroll
        for (int mi = 0; mi < 4; ++mi) {
            bf16x8 afr = *(bf16x8*)&As[(wr * 64 + mi * 16 + row16) * LDW + kg * 16];
            acc[mi][0] = __builtin_amdgcn_mfma_f32_16x16x32_bf16(afr, bfr[0], acc[mi][0], 0, 0, 0);
            acc[mi][1] = __builtin_amdgcn_mfma_f32_16x16x32_bf16(afr, bfr[1], acc[mi][1], 0, 0, 0);
        }
        __syncthreads();
    }
    #pragma unroll
    for (int mi = 0; mi < 4; ++mi)
        #pragma unroll
        for (int ni = 0; ni < 2; ++ni) {
            int rowl = wr * 64 + mi * 16 + kg * 4;
            int coll = wc * 32 + ni * 16 + row16;
            int n = n0 + coll;
            float bc = tcb[n];
            #pragma unroll
            for (int q = 0; q < 4; ++q) {
                size_t node = (size_t)(m0 + rowl + q);
                float v = acc[mi][ni][q] + bc + x[node * 256 + n];
                v = v > 0.f ? v : 0.f;
                hAb[node * 256 + n] = f2b(v);
            }
        }
}

__global__ __launch_bounds__(256) void k_count(const int* __restrict__ ei, int* __restrict__ cnt) {
    int e = blockIdx.x * 256 + threadIdx.x;
    int dst = (e < NE) ? ei[NE + e] : (e - NE);
    atomicAdd(&cnt[dst], 1);
}

__global__ __launch_bounds__(1024) void k_scan(const int* __restrict__ cnt, int* __restrict__ off,
                                               int* __restrict__ cur) {
    __shared__ int sums[1024];
    int t = threadIdx.x;
    int base = t * 16;
    int c[16]; int s = 0;
    #pragma unroll
    for (int j = 0; j < 16; ++j) { c[j] = cnt[base + j]; s += c[j]; }
    sums[t] = s;
    __syncthreads();
    for (int dstep = 1; dstep < 1024; dstep <<= 1) {
        int v = (t >= dstep) ? sums[t - dstep] : 0;
        __syncthreads();
        sums[t] += v;
        __syncthreads();
    }
    int pre = (t == 0) ? 0 : sums[t - 1];
    #pragma unroll
    for (int j = 0; j < 16; ++j) { off[base + j] = pre; cur[base + j] = pre; pre += c[j]; }
    if (t == 1023) off[NTOT] = pre;
}

__global__ __launch_bounds__(256) void k_scatter(const int* __restrict__ ei, int* __restrict__ cur,
                                                 int* __restrict__ csr) {
    int e = blockIdx.x * 256 + threadIdx.x;
    int src, dst;
    if (e < NE) { src = ei[e]; dst = ei[NE + e]; } else { src = dst = e - NE; }
    int pos = atomicAdd(&cur[dst], 1);
    csr[pos] = src;
}

// edge softmax + aggregate: lane-parallel scoring, online softmax, pipelined row gather
__global__ __launch_bounds__(256) void k_agg(const unsigned short* __restrict__ hwB,
                                             const float* __restrict__ sPart, const float* __restrict__ dPart,
                                             const int* __restrict__ off, const int* __restrict__ csr,
                                             const float* __restrict__ bias,
                                             unsigned short* __restrict__ hout) {
    int tid = threadIdx.x;
    int wave = tid >> 6, lane = tid & 63;
    int node = blockIdx.x * 4 + wave;
    int beg = off[node], end = off[node + 1];
    float di = dPart[node] + dPart[NTOT + node] + dPart[2 * NTOT + node] + dPart[3 * NTOT + node];
    const ushort4* hw4 = (const ushort4*)hwB;
    float m = -INFINITY, denom = 0.f;
    float a0 = 0.f, a1 = 0.f, a2 = 0.f, a3 = 0.f;

    for (int cbeg = beg; cbeg < end; cbeg += 64) {
        int j = cbeg + lane;
        int sj = 0;
        float e = -INFINITY;
        if (j < end) {
            sj = csr[j];
            float sv = sPart[sj] + sPart[NTOT + sj] + sPart[2 * NTOT + sj] + sPart[3 * NTOT + sj];
            e = sv + di;
            e = e > 0.f ? e : SLOPE * e;
        }
        float cm = e;
        #pragma unroll
        for (int o = 1; o < 64; o <<= 1) cm = fmaxf(cm, __shfl_xor(cm, o));
        float nm = fmaxf(m, cm);
        float myw = (j < end) ? __expf(e - nm) : 0.f;
        float csum = myw;
        #pragma unroll
        for (int o = 1; o < 64; o <<= 1) csum += __shfl_xor(csum, o);
        float scale = (m > -INFINITY) ? __expf(m - nm) : 0.f;
        denom = denom * scale + csum;
        a0 *= scale; a1 *= scale; a2 *= scale; a3 *= scale;
        m = nm;
        int cnt = end - cbeg; if (cnt > 64) cnt = 64;
        int q = 0;
        for (; q + 4 <= cnt; q += 4) {
            int s0 = __builtin_amdgcn_readlane(sj, q);
            int s1 = __builtin_amdgcn_readlane(sj, q + 1);
            int s2 = __builtin_amdgcn_readlane(sj, q + 2);
            int s3 = __builtin_amdgcn_readlane(sj, q + 3);
            float w0 = rlanef(myw, q);
            float w1 = rlanef(myw, q + 1);
            float w2 = rlanef(myw, q + 2);
            float w3 = rlanef(myw, q + 3);
            ushort4 v0 = hw4[(size_t)s0 * 64 + lane];
            ushort4 v1 = hw4[(size_t)s1 * 64 + lane];
            ushort4 v2 = hw4[(size_t)s2 * 64 + lane];
            ushort4 v3 = hw4[(size_t)s3 * 64 + lane];
            a0 = fmaf(w0, b2f(v0.x), a0); a1 = fmaf(w0, b2f(v0.y), a1);
            a2 = fmaf(w0, b2f(v0.z), a2); a3 = fmaf(w0, b2f(v0.w), a3);
            a0 = fmaf(w1, b2f(v1.x), a0); a1 = fmaf(w1, b2f(v1.y), a1);
            a2 = fmaf(w1, b2f(v1.z), a2); a3 = fmaf(w1, b2f(v1.w), a3);
            a0 = fmaf(w2, b2f(v2.x), a0); a1 = fmaf(w2, b2f(v2.y), a1);
            a2 = fmaf(w2, b2f(v2.z), a2); a3 = fmaf(w2, b2f(v2.w), a3);
            a0 = fmaf(w3, b2f(v3.x), a0); a1 = fmaf(w3, b2f(v3.y), a1);
            a2 = fmaf(w3, b2f(v3.z), a2); a3 = fmaf(w3, b2f(v3.w), a3);
        }
        for (; q < cnt; ++q) {
            int sq = __builtin_amdgcn_readlane(sj, q);
            float wq = rlanef(myw, q);
            ushort4 v = hw4[(size_t)sq * 64 + lane];
            a0 = fmaf(wq, b2f(v.x), a0); a1 = fmaf(wq, b2f(v.y), a1);
            a2 = fmaf(wq, b2f(v.z), a2); a3 = fmaf(wq, b2f(v.w), a3);
        }
    }
    float inv = 1.f / denom;
    float4 bb = ((const float4*)bias)[lane];
    ushort4 o;
    float o0 = a0 * inv + bb.x; o.x = f2b(o0 > 0.f ? o0 : 0.f);
    float o1 = a1 * inv + bb.y; o.y = f2b(o1 > 0.f ? o1 : 0.f);
    float o2 = a2 * inv + bb.z; o.z = f2b(o2 > 0.f ? o2 : 0.f);
    float o3 = a3 * inv + bb.w; o.w = f2b(o3 > 0.f ? o3 : 0.f);
    ((ushort4*)hout)[(size_t)node * 64 + lane] = o;
}

// final conv at n==0 (taps 1,2 on nodes 0,1) + LayerNorm + relu
__global__ __launch_bounds__(256) void k_final(const unsigned short* __restrict__ hAb,
                                               const float* __restrict__ wT,
                                               const float* __restrict__ tcb, const float* __restrict__ g,
                                               const float* __restrict__ bln, float* __restrict__ out) {
    __shared__ float r0[HDIM], r1[HDIM];
    __shared__ float red[16];
    int b = blockIdx.x, c = threadIdx.x;
    r0[c] = b2f(hAb[(size_t)(b * NSEQ + 0) * HDIM + c]);
    r1[c] = b2f(hAb[(size_t)(b * NSEQ + 1) * HDIM + c]);
    __syncthreads();
    float a = tcb[c];
    for (int f = 0; f < FDIM; ++f) {
        a = fmaf(wT[(1 * FDIM + f) * HDIM + c], r0[f], a);
        a = fmaf(wT[(2 * FDIM + f) * HDIM + c], r1[f], a);
    }
    float ss = a, sq = a * a;
    #pragma unroll
    for (int o = 1; o < 64; o <<= 1) { ss += __shfl_xor(ss, o); sq += __shfl_xor(sq, o); }
    int wave = c >> 6, lane = c & 63;
    if (lane == 0) { red[wave] = ss; red[8 + wave] = sq; }
    __syncthreads();
    float tot = 0.f, totq = 0.f;
    #pragma unroll
    for (int w = 0; w < 4; ++w) { tot += red[w]; totq += red[8 + w]; }
    float mu = tot * (1.f / HDIM);
    float var = totq * (1.f / HDIM) - mu * mu;
    float v = (a - mu) * rsqrtf(var + LN_EPS) * g[c] + bln[c];
    out[b * HDIM + c] = v > 0.f ? v : 0.f;
}

extern "C" void kernel_launch(void* const* d_in, const int* in_sizes, int n_in,
                              void* d_out, int out_size, void* d_ws, size_t ws_size,
                              hipStream_t stream) {
    const float* x     = (const float*)d_in[0];
    const int*   ei    = (const int*)d_in[1];
    const float* tcw   = (const float*)d_in[2];
    const float* tcb   = (const float*)d_in[3];
    const float* gatW  = (const float*)d_in[4];
    const float* gatas = (const float*)d_in[5];
    const float* gatad = (const float*)d_in[6];
    const float* gatb  = (const float*)d_in[7];
    const float* lng   = (const float*)d_in[8];
    const float* lnb   = (const float*)d_in[9];
    float* out = (float*)d_out;

    char* ws = (char*)d_ws;
    unsigned short* hAb = (unsigned short*)(ws + OFF_HA);
    unsigned short* hwB = (unsigned short*)(ws + OFF_HW);
    unsigned short* xbf = (unsigned short*)(ws + OFF_XB);
    unsigned short* wcB = (unsigned short*)(ws + OFF_WC);
    unsigned short* WTb = (unsigned short*)(ws + OFF_WL);
    float* sPart = (float*)(ws + OFF_SP);
    float* dPart = (float*)(ws + OFF_DP);
    int*   cnt  = (int*)(ws + OFF_CNT);
    int*   offA = (int*)(ws + OFF_OFF);
    int*   cur  = (int*)(ws + OFF_CUR);
    int*   csr  = (int*)(ws + OFF_CSR);
    float* wT   = (float*)(ws + OFF_WT);

    hipMemsetAsync(cnt, 0, NTOT * sizeof(int), stream);

    k_xbf<<<NTOT * HDIM / 1024, 256, 0, stream>>>(x, xbf);
    k_prep<<<1792, 256, 0, stream>>>(tcw, gatW, wcB, WTb, wT);

    k_count<<<NEE / 256, 256, 0, stream>>>(ei, cnt);
    k_scan<<<1, 1024, 0, stream>>>(cnt, offA, cur);
    k_scatter<<<NEE / 256, 256, 0, stream>>>(ei, cur, csr);

    k_conv_gemm<<<dim3(NTOT / 128, 4), 256, 0, stream>>>(xbf, x, wcB, tcb, hAb);

    for (int l = 0; l < NLAYER; ++l) {
        k_gemm_layer<<<dim3(NTOT / 128, 4), 256, 0, stream>>>(
            hAb, WTb + (size_t)l * 65536, gatas + l * HDIM, gatad + l * HDIM, hwB, sPart, dPart);
        k_agg<<<NTOT / 4, 256, 0, stream>>>(hwB, sPart, dPart, offA, csr, gatb + l * HDIM, hAb);
    }

    k_final<<<BBATCH, 256, 0, stream>>>(hAb, wT, tcb, lng, lnb, out);
}

// Round 4
// 196.140 us; speedup vs baseline: 2.2667x; 1.0206x over previous
//
#include <hip/hip_runtime.h>
#include <hip/hip_bf16.h>
#include <math.h>

#define NTOT 16384
#define HDIM 256
#define BBATCH 4
#define NSEQ 4096
#define FDIM 256
#define NE 262144
#define NEE (NE + NTOT)
#define NLAYER 3
#define LN_EPS 1e-5f
#define SLOPE 0.2f

typedef __attribute__((ext_vector_type(8))) short bf16x8;
typedef __attribute__((ext_vector_type(4))) float f32x4;

#define LDW 80   // LDS row stride in bytes (64B payload + 16B pad -> 2-way bank alias, free)

// ---- workspace layout (bytes) ----
#define OFF_HA   0u          // ushort[NTOT*256]  8388608   node features (bf16)
#define OFF_HW   8388608u    // ushort[NTOT*256]  8388608   hw = h@W (bf16)
#define OFF_XB   16777216u   // ushort[NTOT*256]  8388608   x in bf16
#define OFF_WC   25165824u   // ushort[256*768]   393216    conv weight^T bf16, k = tap*256+f
#define OFF_WL   25559040u   // ushort[3*256*256] 393216    layer W^T bf16
#define OFF_SP   25952256u   // float[4*NTOT]     262144    s partials (per col-block)
#define OFF_DP   26214400u   // float[4*NTOT]     262144    d partials
#define OFF_CNT  26476544u   // int[NTOT]
#define OFF_OFF  26542080u   // int[NTOT+1] (pad 65792)
#define OFF_CUR  26607872u   // int[NTOT]
#define OFF_CSR  26673408u   // int[NEE] 1114112
#define OFF_WT   27787520u   // float[3*256*256] 786432 (fp32 conv weight^T for k_final)
// total 28573952

static __device__ __forceinline__ unsigned short f2b(float f) {
    __hip_bfloat16 h = __float2bfloat16(f);
    return __builtin_bit_cast(unsigned short, h);
}
static __device__ __forceinline__ float b2f(unsigned short u) {
    __hip_bfloat16 h = __builtin_bit_cast(__hip_bfloat16, u);
    return __bfloat162float(h);
}
static __device__ __forceinline__ float rlanef(float v, int l) {
    return __builtin_bit_cast(float, __builtin_amdgcn_readlane(__builtin_bit_cast(int, v), l));
}

// x fp32 -> bf16 ; blocks 0..15 also zero the cnt[] array (replaces hipMemsetAsync,
// whose rocclr fill kernel cost ~44 us/replay on the stream)
__global__ __launch_bounds__(256) void k_xbf(const float* __restrict__ x, unsigned short* __restrict__ xb,
                                             int* __restrict__ cnt) {
    int i = (blockIdx.x * 256 + threadIdx.x) * 4;
    float4 v = *(const float4*)(x + i);
    ushort4 o;
    o.x = f2b(v.x); o.y = f2b(v.y); o.z = f2b(v.z); o.w = f2b(v.w);
    *(ushort4*)(xb + i) = o;
    if (blockIdx.x < 16) {
        int j = (blockIdx.x * 256 + threadIdx.x) * 4;
        *(int4*)(cnt + j) = make_int4(0, 0, 0, 0);
    }
}

// merged weight prep: conv w -> bf16 [c][tap*256+f]; gat W -> bf16 W^T; conv w -> fp32 wT[k][f][c]
__global__ __launch_bounds__(256) void k_prep(const float* __restrict__ tcw, const float* __restrict__ gatW,
                                              unsigned short* __restrict__ wcB, unsigned short* __restrict__ WTb,
                                              float* __restrict__ wT) {
    int b = blockIdx.x, t = threadIdx.x;
    if (b < 256) {
        const float* s = tcw + b * 768 + t * 3;
        wcB[b * 768 + 0 + t]   = f2b(s[0]);
        wcB[b * 768 + 256 + t] = f2b(s[1]);
        wcB[b * 768 + 512 + t] = f2b(s[2]);
    } else if (b < 1024) {
        int ln = b - 256; int n = ln & 255; int l = ln >> 8;
        WTb[(size_t)l * 65536 + n * 256 + t] = f2b(gatW[(size_t)l * 65536 + t * 256 + n]);
    } else {
        int fk = b - 1024; int f = fk / 3, k = fk - 3 * f;
        wT[(k * FDIM + f) * HDIM + t] = tcw[t * 768 + fk];
    }
}

// ---------------- MFMA GEMM: hw = h @ W (M=16384,N=256,K=256) + fused s/d partials ----------------
__global__ __launch_bounds__(256) void k_gemm_layer(const unsigned short* __restrict__ hAb,
                                                    const unsigned short* __restrict__ WT,
                                                    const float* __restrict__ as, const float* __restrict__ ad,
                                                    unsigned short* __restrict__ hwB,
                                                    float* __restrict__ sPart, float* __restrict__ dPart) {
    __shared__ char lds[128 * LDW + 64 * LDW];
    __shared__ float sRed[256], dRed[256];
    char* As = lds;
    char* Bs = lds + 128 * LDW;
    int t = threadIdx.x;
    int m0 = blockIdx.x * 128, n0 = blockIdx.y * 64;
    int w = t >> 6, lane = t & 63;
    int wr = w >> 1, wc = w & 1;
    int row16 = lane & 15, kg = lane >> 4;
    int rA = t >> 1, hh = t & 1;
    f32x4 acc[4][2];
    #pragma unroll
    for (int mi = 0; mi < 4; ++mi)
        #pragma unroll
        for (int ni = 0; ni < 2; ++ni) acc[mi][ni] = (f32x4)(0.f);

    for (int kb = 0; kb < 256; kb += 32) {
        {
            const uint4* src = (const uint4*)(hAb + (size_t)(m0 + rA) * 256 + kb + hh * 16);
            uint4 v0 = src[0], v1 = src[1];
            *(uint4*)&As[rA * LDW + hh * 32] = v0;
            *(uint4*)&As[rA * LDW + hh * 32 + 16] = v1;
        }
        if (t < 128) {
            int rB = t >> 1;
            const uint4* src = (const uint4*)(WT + (size_t)(n0 + rB) * 256 + kb + hh * 16);
            uint4 v0 = src[0], v1 = src[1];
            *(uint4*)&Bs[rB * LDW + hh * 32] = v0;
            *(uint4*)&Bs[rB * LDW + hh * 32 + 16] = v1;
        }
        __syncthreads();
        bf16x8 bfr[2];
        #pragma unroll
        for (int ni = 0; ni < 2; ++ni)
            bfr[ni] = *(bf16x8*)&Bs[(wc * 32 + ni * 16 + row16) * LDW + kg * 16];
        #pragma unroll
        for (int mi = 0; mi < 4; ++mi) {
            bf16x8 afr = *(bf16x8*)&As[(wr * 64 + mi * 16 + row16) * LDW + kg * 16];
            acc[mi][0] = __builtin_amdgcn_mfma_f32_16x16x32_bf16(afr, bfr[0], acc[mi][0], 0, 0, 0);
            acc[mi][1] = __builtin_amdgcn_mfma_f32_16x16x32_bf16(afr, bfr[1], acc[mi][1], 0, 0, 0);
        }
        __syncthreads();
    }
    // hw store
    #pragma unroll
    for (int mi = 0; mi < 4; ++mi)
        #pragma unroll
        for (int ni = 0; ni < 2; ++ni) {
            int rowl = wr * 64 + mi * 16 + kg * 4;
            int coll = wc * 32 + ni * 16 + row16;
            size_t base = (size_t)(m0 + rowl) * 256 + n0 + coll;
            #pragma unroll
            for (int q = 0; q < 4; ++q) hwB[base + (size_t)q * 256] = f2b(acc[mi][ni][q]);
        }
    // fused s/d partials over this block's 64 cols
    float asv0 = as[n0 + wc * 32 + row16];
    float asv1 = as[n0 + wc * 32 + 16 + row16];
    float adv0 = ad[n0 + wc * 32 + row16];
    float adv1 = ad[n0 + wc * 32 + 16 + row16];
    #pragma unroll
    for (int mi = 0; mi < 4; ++mi)
        #pragma unroll
        for (int q = 0; q < 4; ++q) {
            float ps = acc[mi][0][q] * asv0 + acc[mi][1][q] * asv1;
            float pd = acc[mi][0][q] * adv0 + acc[mi][1][q] * adv1;
            #pragma unroll
            for (int o = 1; o < 16; o <<= 1) { ps += __shfl_xor(ps, o); pd += __shfl_xor(pd, o); }
            if (row16 == 0) {
                int rowl = wr * 64 + mi * 16 + kg * 4 + q;
                sRed[rowl * 2 + wc] = ps;
                dRed[rowl * 2 + wc] = pd;
            }
        }
    __syncthreads();
    if (t < 128) {
        sPart[(size_t)blockIdx.y * NTOT + m0 + t] = sRed[t * 2] + sRed[t * 2 + 1];
        dPart[(size_t)blockIdx.y * NTOT + m0 + t] = dRed[t * 2] + dRed[t * 2 + 1];
    }
}

// ---------------- MFMA conv GEMM: M=16384, N=256, K=768 (k = tap*256+f) ----------------
__global__ __launch_bounds__(256) void k_conv_gemm(const unsigned short* __restrict__ xbf,
                                                   const float* __restrict__ x,
                                                   const unsigned short* __restrict__ wcB,
                                                   const float* __restrict__ tcb,
                                                   unsigned short* __restrict__ hAb) {
    __shared__ char lds[128 * LDW + 64 * LDW];
    char* As = lds;
    char* Bs = lds + 128 * LDW;
    int t = threadIdx.x;
    int m0 = blockIdx.x * 128, n0 = blockIdx.y * 64;
    int bb = m0 >> 12;
    int nloc0 = m0 & 4095;
    int w = t >> 6, lane = t & 63;
    int wr = w >> 1, wc = w & 1;
    int row16 = lane & 15, kg = lane >> 4;
    int rA = t >> 1, hh = t & 1;
    f32x4 acc[4][2];
    #pragma unroll
    for (int mi = 0; mi < 4; ++mi)
        #pragma unroll
        for (int ni = 0; ni < 2; ++ni) acc[mi][ni] = (f32x4)(0.f);

    for (int kb = 0; kb < 768; kb += 32) {
        int tap = kb >> 8;
        int fb = kb & 255;
        {
            int nl = nloc0 + rA + tap - 1;
            uint4 v0 = make_uint4(0, 0, 0, 0), v1 = make_uint4(0, 0, 0, 0);
            if ((unsigned)nl < 4096u) {
                const uint4* src = (const uint4*)(xbf + ((size_t)(bb << 12) + nl) * 256 + fb + hh * 16);
                v0 = src[0]; v1 = src[1];
            }
            *(uint4*)&As[rA * LDW + hh * 32] = v0;
            *(uint4*)&As[rA * LDW + hh * 32 + 16] = v1;
        }
        if (t < 128) {
            int rB = t >> 1;
            const uint4* src = (const uint4*)(wcB + (size_t)(n0 + rB) * 768 + kb + hh * 16);
            uint4 v0 = src[0], v1 = src[1];
            *(uint4*)&Bs[rB * LDW + hh * 32] = v0;
            *(uint4*)&Bs[rB * LDW + hh * 32 + 16] = v1;
        }
        __syncthreads();
        bf16x8 bfr[2];
        #pragma unroll
        for (int ni = 0; ni < 2; ++ni)
            bfr[ni] = *(bf16x8*)&Bs[(wc * 32 + ni * 16 + row16) * LDW + kg * 16];
        #pragma unroll
        for (int mi = 0; mi < 4; ++mi) {
            bf16x8 afr = *(bf16x8*)&As[(wr * 64 + mi * 16 + row16) * LDW + kg * 16];
            acc[mi][0] = __builtin_amdgcn_mfma_f32_16x16x32_bf16(afr, bfr[0], acc[mi][0], 0, 0, 0);
            acc[mi][1] = __builtin_amdgcn_mfma_f32_16x16x32_bf16(afr, bfr[1], acc[mi][1], 0, 0, 0);
        }
        __syncthreads();
    }
    #pragma unroll
    for (int mi = 0; mi < 4; ++mi)
        #pragma unroll
        for (int ni = 0; ni < 2; ++ni) {
            int rowl = wr * 64 + mi * 16 + kg * 4;
            int coll = wc * 32 + ni * 16 + row16;
            int n = n0 + coll;
            float bc = tcb[n];
            #pragma unroll
            for (int q = 0; q < 4; ++q) {
                size_t node = (size_t)(m0 + rowl + q);
                float v = acc[mi][ni][q] + bc + x[node * 256 + n];
                v = v > 0.f ? v : 0.f;
                hAb[node * 256 + n] = f2b(v);
            }
        }
}

__global__ __launch_bounds__(256) void k_count(const int* __restrict__ ei, int* __restrict__ cnt) {
    int e = blockIdx.x * 256 + threadIdx.x;
    int dst = (e < NE) ? ei[NE + e] : (e - NE);
    atomicAdd(&cnt[dst], 1);
}

__global__ __launch_bounds__(1024) void k_scan(const int* __restrict__ cnt, int* __restrict__ off,
                                               int* __restrict__ cur) {
    __shared__ int sums[1024];
    int t = threadIdx.x;
    int base = t * 16;
    int c[16]; int s = 0;
    #pragma unroll
    for (int j = 0; j < 16; ++j) { c[j] = cnt[base + j]; s += c[j]; }
    sums[t] = s;
    __syncthreads();
    for (int dstep = 1; dstep < 1024; dstep <<= 1) {
        int v = (t >= dstep) ? sums[t - dstep] : 0;
        __syncthreads();
        sums[t] += v;
        __syncthreads();
    }
    int pre = (t == 0) ? 0 : sums[t - 1];
    #pragma unroll
    for (int j = 0; j < 16; ++j) { off[base + j] = pre; cur[base + j] = pre; pre += c[j]; }
    if (t == 1023) off[NTOT] = pre;
}

__global__ __launch_bounds__(256) void k_scatter(const int* __restrict__ ei, int* __restrict__ cur,
                                                 int* __restrict__ csr) {
    int e = blockIdx.x * 256 + threadIdx.x;
    int src, dst;
    if (e < NE) { src = ei[e]; dst = ei[NE + e]; } else { src = dst = e - NE; }
    int pos = atomicAdd(&cur[dst], 1);
    csr[pos] = src;
}

// edge softmax + aggregate: lane-parallel scoring, online softmax, pipelined row gather
__global__ __launch_bounds__(256) void k_agg(const unsigned short* __restrict__ hwB,
                                             const float* __restrict__ sPart, const float* __restrict__ dPart,
                                             const int* __restrict__ off, const int* __restrict__ csr,
                                             const float* __restrict__ bias,
                                             unsigned short* __restrict__ hout) {
    int tid = threadIdx.x;
    int wave = tid >> 6, lane = tid & 63;
    int node = blockIdx.x * 4 + wave;
    int beg = off[node], end = off[node + 1];
    float di = dPart[node] + dPart[NTOT + node] + dPart[2 * NTOT + node] + dPart[3 * NTOT + node];
    const ushort4* hw4 = (const ushort4*)hwB;
    float m = -INFINITY, denom = 0.f;
    float a0 = 0.f, a1 = 0.f, a2 = 0.f, a3 = 0.f;

    for (int cbeg = beg; cbeg < end; cbeg += 64) {
        int j = cbeg + lane;
        int sj = 0;
        float e = -INFINITY;
        if (j < end) {
            sj = csr[j];
            float sv = sPart[sj] + sPart[NTOT + sj] + sPart[2 * NTOT + sj] + sPart[3 * NTOT + sj];
            e = sv + di;
            e = e > 0.f ? e : SLOPE * e;
        }
        float cm = e;
        #pragma unroll
        for (int o = 1; o < 64; o <<= 1) cm = fmaxf(cm, __shfl_xor(cm, o));
        float nm = fmaxf(m, cm);
        float myw = (j < end) ? __expf(e - nm) : 0.f;
        float csum = myw;
        #pragma unroll
        for (int o = 1; o < 64; o <<= 1) csum += __shfl_xor(csum, o);
        float scale = (m > -INFINITY) ? __expf(m - nm) : 0.f;
        denom = denom * scale + csum;
        a0 *= scale; a1 *= scale; a2 *= scale; a3 *= scale;
        m = nm;
        int cnt = end - cbeg; if (cnt > 64) cnt = 64;
        int q = 0;
        for (; q + 4 <= cnt; q += 4) {
            int s0 = __builtin_amdgcn_readlane(sj, q);
            int s1 = __builtin_amdgcn_readlane(sj, q + 1);
            int s2 = __builtin_amdgcn_readlane(sj, q + 2);
            int s3 = __builtin_amdgcn_readlane(sj, q + 3);
            float w0 = rlanef(myw, q);
            float w1 = rlanef(myw, q + 1);
            float w2 = rlanef(myw, q + 2);
            float w3 = rlanef(myw, q + 3);
            ushort4 v0 = hw4[(size_t)s0 * 64 + lane];
            ushort4 v1 = hw4[(size_t)s1 * 64 + lane];
            ushort4 v2 = hw4[(size_t)s2 * 64 + lane];
            ushort4 v3 = hw4[(size_t)s3 * 64 + lane];
            a0 = fmaf(w0, b2f(v0.x), a0); a1 = fmaf(w0, b2f(v0.y), a1);
            a2 = fmaf(w0, b2f(v0.z), a2); a3 = fmaf(w0, b2f(v0.w), a3);
            a0 = fmaf(w1, b2f(v1.x), a0); a1 = fmaf(w1, b2f(v1.y), a1);
            a2 = fmaf(w1, b2f(v1.z), a2); a3 = fmaf(w1, b2f(v1.w), a3);
            a0 = fmaf(w2, b2f(v2.x), a0); a1 = fmaf(w2, b2f(v2.y), a1);
            a2 = fmaf(w2, b2f(v2.z), a2); a3 = fmaf(w2, b2f(v2.w), a3);
            a0 = fmaf(w3, b2f(v3.x), a0); a1 = fmaf(w3, b2f(v3.y), a1);
            a2 = fmaf(w3, b2f(v3.z), a2); a3 = fmaf(w3, b2f(v3.w), a3);
        }
        for (; q < cnt; ++q) {
            int sq = __builtin_amdgcn_readlane(sj, q);
            float wq = rlanef(myw, q);
            ushort4 v = hw4[(size_t)sq * 64 + lane];
            a0 = fmaf(wq, b2f(v.x), a0); a1 = fmaf(wq, b2f(v.y), a1);
            a2 = fmaf(wq, b2f(v.z), a2); a3 = fmaf(wq, b2f(v.w), a3);
        }
    }
    float inv = 1.f / denom;
    float4 bb = ((const float4*)bias)[lane];
    ushort4 o;
    float o0 = a0 * inv + bb.x; o.x = f2b(o0 > 0.f ? o0 : 0.f);
    float o1 = a1 * inv + bb.y; o.y = f2b(o1 > 0.f ? o1 : 0.f);
    float o2 = a2 * inv + bb.z; o.z = f2b(o2 > 0.f ? o2 : 0.f);
    float o3 = a3 * inv + bb.w; o.w = f2b(o3 > 0.f ? o3 : 0.f);
    ((ushort4*)hout)[(size_t)node * 64 + lane] = o;
}

// final conv at n==0 (taps 1,2 on nodes 0,1) + LayerNorm + relu
__global__ __launch_bounds__(256) void k_final(const unsigned short* __restrict__ hAb,
                                               const float* __restrict__ wT,
                                               const float* __restrict__ tcb, const float* __restrict__ g,
                                               const float* __restrict__ bln, float* __restrict__ out) {
    __shared__ float r0[HDIM], r1[HDIM];
    __shared__ float red[16];
    int b = blockIdx.x, c = threadIdx.x;
    r0[c] = b2f(hAb[(size_t)(b * NSEQ + 0) * HDIM + c]);
    r1[c] = b2f(hAb[(size_t)(b * NSEQ + 1) * HDIM + c]);
    __syncthreads();
    float a = tcb[c];
    for (int f = 0; f < FDIM; ++f) {
        a = fmaf(wT[(1 * FDIM + f) * HDIM + c], r0[f], a);
        a = fmaf(wT[(2 * FDIM + f) * HDIM + c], r1[f], a);
    }
    float ss = a, sq = a * a;
    #pragma unroll
    for (int o = 1; o < 64; o <<= 1) { ss += __shfl_xor(ss, o); sq += __shfl_xor(sq, o); }
    int wave = c >> 6, lane = c & 63;
    if (lane == 0) { red[wave] = ss; red[8 + wave] = sq; }
    __syncthreads();
    float tot = 0.f, totq = 0.f;
    #pragma unroll
    for (int w = 0; w < 4; ++w) { tot += red[w]; totq += red[8 + w]; }
    float mu = tot * (1.f / HDIM);
    float var = totq * (1.f / HDIM) - mu * mu;
    float v = (a - mu) * rsqrtf(var + LN_EPS) * g[c] + bln[c];
    out[b * HDIM + c] = v > 0.f ? v : 0.f;
}

extern "C" void kernel_launch(void* const* d_in, const int* in_sizes, int n_in,
                              void* d_out, int out_size, void* d_ws, size_t ws_size,
                              hipStream_t stream) {
    const float* x     = (const float*)d_in[0];
    const int*   ei    = (const int*)d_in[1];
    const float* tcw   = (const float*)d_in[2];
    const float* tcb   = (const float*)d_in[3];
    const float* gatW  = (const float*)d_in[4];
    const float* gatas = (const float*)d_in[5];
    const float* gatad = (const float*)d_in[6];
    const float* gatb  = (const float*)d_in[7];
    const float* lng   = (const float*)d_in[8];
    const float* lnb   = (const float*)d_in[9];
    float* out = (float*)d_out;

    char* ws = (char*)d_ws;
    unsigned short* hAb = (unsigned short*)(ws + OFF_HA);
    unsigned short* hwB = (unsigned short*)(ws + OFF_HW);
    unsigned short* xbf = (unsigned short*)(ws + OFF_XB);
    unsigned short* wcB = (unsigned short*)(ws + OFF_WC);
    unsigned short* WTb = (unsigned short*)(ws + OFF_WL);
    float* sPart = (float*)(ws + OFF_SP);
    float* dPart = (float*)(ws + OFF_DP);
    int*   cnt  = (int*)(ws + OFF_CNT);
    int*   offA = (int*)(ws + OFF_OFF);
    int*   cur  = (int*)(ws + OFF_CUR);
    int*   csr  = (int*)(ws + OFF_CSR);
    float* wT   = (float*)(ws + OFF_WT);

    k_xbf<<<NTOT * HDIM / 1024, 256, 0, stream>>>(x, xbf, cnt);
    k_prep<<<1792, 256, 0, stream>>>(tcw, gatW, wcB, WTb, wT);

    k_count<<<NEE / 256, 256, 0, stream>>>(ei, cnt);
    k_scan<<<1, 1024, 0, stream>>>(cnt, offA, cur);
    k_scatter<<<NEE / 256, 256, 0, stream>>>(ei, cur, csr);

    k_conv_gemm<<<dim3(NTOT / 128, 4), 256, 0, stream>>>(xbf, x, wcB, tcb, hAb);

    for (int l = 0; l < NLAYER; ++l) {
        k_gemm_layer<<<dim3(NTOT / 128, 4), 256, 0, stream>>>(
            hAb, WTb + (size_t)l * 65536, gatas + l * HDIM, gatad + l * HDIM, hwB, sPart, dPart);
        k_agg<<<NTOT / 4, 256, 0, stream>>>(hwB, sPart, dPart, offA, csr, gatb + l * HDIM, hAb);
    }

    k_final<<<BBATCH, 256, 0, stream>>>(hAb, wT, tcb, lng, lnb, out);
}